// Round 12
// baseline (237.259 us; speedup 1.0000x reference)
//
#include <hip/hip_runtime.h>
#include <stdint.h>

// Problem constants (fp32 inputs/outputs)
#define Bb 2
#define Ss 1024
#define Dd 512
#define Hh 8
#define HD 4096   // Hh*Dd
#define Mm 2048   // Bb*Ss

typedef _Float16 f16x8 __attribute__((ext_vector_type(8)));
typedef _Float16 f16x4 __attribute__((ext_vector_type(4)));
typedef float    f32x4 __attribute__((ext_vector_type(4)));

#define LOG2E 1.44269504f

// async global->LDS, 16B per lane. dest must be linear: base + lane*16.
#define GLOAD16(g, l)                                                          \
    __builtin_amdgcn_global_load_lds(                                          \
        (const __attribute__((address_space(1))) void*)(g),                    \
        (__attribute__((address_space(3))) void*)(l), 16, 0, 0)

// ---------------------------------------------------------------------------
// cvt_f16: fp32 -> f16 elementwise. n multiple of 1024. (HG=4 fallback)
// ---------------------------------------------------------------------------
__global__ __launch_bounds__(256) void cvt_f16(
    const float* __restrict__ in, _Float16* __restrict__ out, int n)
{
    int i = (blockIdx.x * 256 + threadIdx.x) * 4;
    if (i < n) {
        float4 u = *(const float4*)(in + i);
        f16x4 o;
        o[0] = (_Float16)u.x; o[1] = (_Float16)u.y;
        o[2] = (_Float16)u.z; o[3] = (_Float16)u.w;
        *(f16x4*)(out + i) = o;
    }
}

// ---------------------------------------------------------------------------
// cvt_w_pk: W fp32 [512][ld], cols [col0, col0+NC) -> f16 k-pack8 (HG=4 path)
// ---------------------------------------------------------------------------
__global__ __launch_bounds__(256) void cvt_w_pk(
    const float* __restrict__ W, int ld, int col0,
    _Float16* __restrict__ out, int NC)
{
    const int n  = blockIdx.x * 256 + threadIdx.x;
    const int k0 = blockIdx.y * 8;
    f16x8 o;
#pragma unroll
    for (int j = 0; j < 8; j++)
        o[j] = (_Float16)W[(size_t)(k0 + j) * ld + col0 + n];
    *(f16x8*)(out + ((size_t)(k0 >> 3) * NC + n) * 8) = o;
}

// ---------------------------------------------------------------------------
// stage_all (HG=8): one flat grid doing ALL input staging.
//   jobs [0,1024)      : x fp32->f16   (1024 elems/block)
//   jobs [1024,2048)   : y fp32->f16
//   jobs [2048,5120)   : Wq/Wk/Wv -> k-pack8 (1024 blocks each, 16x64 decode)
//   jobs [5120,5248)   : Wp -> k-pack8       (128 blocks, 2x64 decode)
// ---------------------------------------------------------------------------
__global__ __launch_bounds__(256) void stage_all(
    const float* __restrict__ x, const float* __restrict__ y,
    const float* __restrict__ Wq, const float* __restrict__ Wk,
    const float* __restrict__ Wv, const float* __restrict__ Wp,
    _Float16* __restrict__ xf, _Float16* __restrict__ yf,
    _Float16* __restrict__ Wbuf, int NCq, size_t wslot)
{
    const int f = blockIdx.x;
    if (f < 2048) {
        const float* in = (f < 1024) ? x : y;
        _Float16* out   = (f < 1024) ? xf : yf;
        const int i = ((f & 1023) * 256 + threadIdx.x) * 4;
        float4 u = *(const float4*)(in + i);
        f16x4 o;
        o[0] = (_Float16)u.x; o[1] = (_Float16)u.y;
        o[2] = (_Float16)u.z; o[3] = (_Float16)u.w;
        *(f16x4*)(out + i) = o;
        return;
    }
    int l = f - 2048;
    const float* W; int ld, NCz, z, bx, by;
    if (l < 3072) {
        z = l >> 10; l &= 1023;
        W = (z == 0) ? Wq : (z == 1) ? Wk : Wv; ld = HD; NCz = NCq;
        bx = l & 15; by = l >> 4;
    } else {
        z = 3; l -= 3072;
        W = Wp; ld = Dd; NCz = Dd;
        bx = l & 1; by = l >> 1;
    }
    const int n  = bx * 256 + threadIdx.x;
    const int k0 = by * 8;
    f16x8 o;
#pragma unroll
    for (int j = 0; j < 8; j++)
        o[j] = (_Float16)W[(size_t)(k0 + j) * ld + n];
    *(f16x8*)(Wbuf + (size_t)z * wslot + ((size_t)(k0 >> 3) * NCz + n) * 8) = o;
}

// ---------------------------------------------------------------------------
// proj_body: C[2048, NC] = A[2048,512](f16 row-major) @ Wpk(k-pack8) + bias.
// 128x128 tile, 4 waves, 64x64/wave, 2-phase dbuf LDS via global_load_lds.
// packC=1 stores f16x4 (pack8 rows r=0..3 contiguous halves).
// ---------------------------------------------------------------------------
__device__ __forceinline__ void proj_body(
    const _Float16* __restrict__ A, const _Float16* __restrict__ Wpk,
    const float* __restrict__ bias, int bias0,
    _Float16* __restrict__ C, int NC, int packC, int bx, int by)
{
    __shared__ _Float16 lsA[2][4096];
    __shared__ _Float16 lsB[2][4096];
    const int t = threadIdx.x;
    const int lane = t & 63, wave = t >> 6;
    const int quad = lane >> 4, l15 = lane & 15;
    const int m0b = by * 128, n0b = bx * 128;
    const int aw = (wave >> 1) * 64, bw = (wave & 1) * 64;
    const int qx = (quad ^ ((l15 >> 2) & 3)) * 8;

    const _Float16* ag = A + (size_t)(m0b + (t >> 2)) * Dd
                           + ((t & 3) ^ ((t >> 4) & 3)) * 8;
    const _Float16* bg = Wpk + ((size_t)(t >> 7) * NC + n0b + (t & 127)) * 8;
    const size_t arj = (size_t)64 * Dd;
    const size_t bcs = (size_t)NC * 8;

    f32x4 acc[4][4] = {};
    GLOAD16(ag,           &lsA[0][t * 8]);
    GLOAD16(ag + arj,     &lsA[0][t * 8 + 2048]);
    GLOAD16(bg,           &lsB[0][t * 8]);
    GLOAD16(bg + 2 * bcs, &lsB[0][t * 8 + 2048]);
    __syncthreads();
    int cur = 0;
    for (int kb = 0; kb < Dd; kb += 32) {
        if (kb + 32 < Dd) {
            const int nb = cur ^ 1;
            GLOAD16(ag + kb + 32,       &lsA[nb][t * 8]);
            GLOAD16(ag + arj + kb + 32, &lsA[nb][t * 8 + 2048]);
            GLOAD16(bg + (size_t)((kb >> 3) + 4) * bcs, &lsB[nb][t * 8]);
            GLOAD16(bg + (size_t)((kb >> 3) + 6) * bcs, &lsB[nb][t * 8 + 2048]);
        }
        f16x8 af[4], bf[4];
#pragma unroll
        for (int mi = 0; mi < 4; mi++)
            af[mi] = *(const f16x8*)&lsA[cur][(aw + mi * 16 + l15) * 32 + qx];
#pragma unroll
        for (int ni = 0; ni < 4; ni++)
            bf[ni] = *(const f16x8*)&lsB[cur][quad * 1024 + (bw + ni * 16 + l15) * 8];
#pragma unroll
        for (int mi = 0; mi < 4; mi++)
#pragma unroll
            for (int ni = 0; ni < 4; ni++)
                acc[mi][ni] = __builtin_amdgcn_mfma_f32_16x16x32_f16(af[mi], bf[ni], acc[mi][ni], 0, 0, 0);
        __syncthreads();
        cur ^= 1;
    }

#pragma unroll
    for (int mi = 0; mi < 4; mi++) {
        const int row0 = m0b + aw + mi * 16 + quad * 4;
#pragma unroll
        for (int ni = 0; ni < 4; ni++) {
            const int col = n0b + bw + ni * 16 + l15;
            const float bv = bias ? bias[bias0 + col] : 0.0f;
            if (packC) {
                f16x4 o;
#pragma unroll
                for (int r = 0; r < 4; r++) o[r] = (_Float16)(acc[mi][ni][r] + bv);
                *(f16x4*)(C + ((size_t)(row0 >> 3) * NC + col) * 8 + (row0 & 7)) = o;
            } else {
#pragma unroll
                for (int r = 0; r < 4; r++)
                    C[(size_t)(row0 + r) * NC + col] = (_Float16)(acc[mi][ni][r] + bv);
            }
        }
    }
}

__global__ __launch_bounds__(256, 5) void proj_f16(
    const _Float16* __restrict__ A, const _Float16* __restrict__ Wpk,
    const float* __restrict__ bias, int bias0,
    _Float16* __restrict__ C, int NC, int packC)
{
    proj_body(A, Wpk, bias, bias0, C, NC, packC, blockIdx.x, blockIdx.y);
}

// fused q/k/v/xp projection (HG=8 only, NC=4096): FLAT 1600-block grid —
// jobs 0..1535 = q/k/v 128x128 tiles (512 each), 1536..1599 = xp tiles.
// launch_bounds(256,5): LDS 32KB x5 = 160KB fits exactly -> capacity 1280
// blocks (1.25 residency rounds vs 1.56 at 4/CU).
__global__ __launch_bounds__(256, 5) void proj_flat(
    const _Float16* __restrict__ xf, const _Float16* __restrict__ yf,
    const _Float16* __restrict__ Wpk, size_t wslot,
    const float* __restrict__ bq, const float* __restrict__ bk,
    const float* __restrict__ bv,
    _Float16* __restrict__ qb, _Float16* __restrict__ kb,
    _Float16* __restrict__ vb, _Float16* __restrict__ xp)
{
    const int f = blockIdx.x;
    int z, bx, by;
    if (f < 1536) { z = f >> 9; const int r = f & 511; bx = r & 31; by = r >> 5; }
    else         { z = 3;      const int r = f - 1536; bx = r & 3;  by = r >> 2; }
    const _Float16* A = (z == 0 || z == 3) ? xf : yf;
    const _Float16* W = Wpk + (size_t)z * wslot;
    const float* bias = (z == 0) ? bq : (z == 1) ? bk : (z == 2) ? bv : nullptr;
    _Float16* C = (z == 0) ? qb : (z == 1) ? kb : (z == 2) ? vb : xp;
    const int NCz = (z == 3) ? Dd : (Hh * Dd);
    proj_body(A, W, bias, 0, C, NCz, z == 2, bx, by);
}

// ---------------------------------------------------------------------------
// energy_f16: E[s,t] = sum_c q[s,c]*k[t,c]; masked t -> -30000.
// A = Q rows (M = s), B = K rows (N = t). STORES P_un = f16(exp(E - m))
// per (s, 64-t-chunk) in s-pack8 layout (reuses the exps already computed
// for the sum partials). Stats (m, l = sum exp) from f16-ROUNDED values.
// pv multiplies by scale[s] = exp(m_chunk - C_s) to recover P.
// Grid (NZ, 8, 8): z in blockIdx.x (XCD affinity).
// ---------------------------------------------------------------------------
__global__ __launch_bounds__(256, 5) void energy_f16(
    const _Float16* __restrict__ Q, const _Float16* __restrict__ Kb,
    const int* __restrict__ mask, _Float16* __restrict__ E,
    float* __restrict__ part, int NC)
{
    __shared__ _Float16 lsA[2][4096];
    __shared__ _Float16 lsB[2][4096];
    const int zl = blockIdx.x;
    const int b = zl & 1, hloc = zl >> 1;
    const _Float16* qz = Q + (size_t)b * Ss * NC + hloc * Dd;
    const _Float16* kz = Kb + (size_t)b * Ss * NC + hloc * Dd;
    _Float16* Ez = E + (size_t)zl * Ss * Ss;

    const int t = threadIdx.x;
    const int lane = t & 63, wave = t >> 6;
    const int quad = lane >> 4, l15 = lane & 15;
    const int sb = blockIdx.y * 128;    // s-block (A / M side, from Q)
    const int tb = blockIdx.z * 128;    // t-block (B / N side, from K)
    const int sw = (wave >> 1) * 64, tw = (wave & 1) * 64;
    const int qx = (quad ^ ((l15 >> 2) & 3)) * 8;

    const int sc = ((t & 3) ^ ((t >> 4) & 3)) * 8;   // pre-swizzled src chunk
    const _Float16* ag = qz + (size_t)(sb + (t >> 2)) * NC + sc;
    const _Float16* bg = kz + (size_t)(tb + (t >> 2)) * NC + sc;
    const size_t rj = (size_t)64 * NC;

    f32x4 acc[4][4] = {};
    GLOAD16(ag,      &lsA[0][t * 8]);
    GLOAD16(ag + rj, &lsA[0][t * 8 + 2048]);
    GLOAD16(bg,      &lsB[0][t * 8]);
    GLOAD16(bg + rj, &lsB[0][t * 8 + 2048]);
    __syncthreads();
    int cur = 0;
    for (int kb = 0; kb < Dd; kb += 32) {
        if (kb + 32 < Dd) {
            const int nb = cur ^ 1;
            GLOAD16(ag + kb + 32,      &lsA[nb][t * 8]);
            GLOAD16(ag + rj + kb + 32, &lsA[nb][t * 8 + 2048]);
            GLOAD16(bg + kb + 32,      &lsB[nb][t * 8]);
            GLOAD16(bg + rj + kb + 32, &lsB[nb][t * 8 + 2048]);
        }
        f16x8 af[4], bf[4];
#pragma unroll
        for (int mi = 0; mi < 4; mi++)
            af[mi] = *(const f16x8*)&lsA[cur][(sw + mi * 16 + l15) * 32 + qx];
#pragma unroll
        for (int ni = 0; ni < 4; ni++)
            bf[ni] = *(const f16x8*)&lsB[cur][(tw + ni * 16 + l15) * 32 + qx];
#pragma unroll
        for (int mi = 0; mi < 4; mi++)
#pragma unroll
            for (int ni = 0; ni < 4; ni++)
                acc[mi][ni] = __builtin_amdgcn_mfma_f32_16x16x32_f16(af[mi], bf[ni], acc[mi][ni], 0, 0, 0);
        __syncthreads();
        cur ^= 1;
    }

    // ---- mask (per column t) + round to f16 in place ----
#pragma unroll
    for (int ni = 0; ni < 4; ni++) {
        const int tcol = tb + tw + ni * 16 + l15;
        const int keep = mask[tcol];
#pragma unroll
        for (int mi = 0; mi < 4; mi++)
#pragma unroll
            for (int r = 0; r < 4; r++) {
                const float v = keep ? acc[mi][ni][r] : -30000.0f;
                acc[mi][ni][r] = (float)(_Float16)v;
            }
    }

    // ---- per-(s, 64-t-chunk): m, then store P_un = exp(E - m), then l ----
    const int jc = blockIdx.z * 2 + (wave & 1);          // t-chunk id 0..15
    float* ps = part + ((size_t)(zl * 16 + jc) * 1024) * 2;
#pragma unroll
    for (int mi = 0; mi < 4; mi++) {
        const int s0 = sb + sw + mi * 16 + quad * 4;
        _Float16* base = Ez + (size_t)(s0 >> 3) * (Ss * 8) + (s0 & 7);
        float m[4], l[4];
#pragma unroll
        for (int r = 0; r < 4; r++) {
            float mm = fmaxf(fmaxf(acc[mi][0][r], acc[mi][1][r]),
                             fmaxf(acc[mi][2][r], acc[mi][3][r]));
#pragma unroll
            for (int off = 1; off < 16; off <<= 1) mm = fmaxf(mm, __shfl_xor(mm, off));
            m[r] = mm;
            l[r] = 0.0f;
        }
#pragma unroll
        for (int ni = 0; ni < 4; ni++) {
            const int tcol = tb + tw + ni * 16 + l15;
            f16x4 o;
#pragma unroll
            for (int r = 0; r < 4; r++) {
                const float p = __expf(acc[mi][ni][r] - m[r]);
                l[r] += p;
                o[r] = (_Float16)p;
            }
            *(f16x4*)(base + (size_t)tcol * 8) = o;
        }
#pragma unroll
        for (int r = 0; r < 4; r++) {
            float ll = l[r];
#pragma unroll
            for (int off = 1; off < 16; off <<= 1) ll += __shfl_xor(ll, off);
            if (l15 == 0) {
                const int s = s0 + r;
                ps[s * 2]     = m[r];
                ps[s * 2 + 1] = ll;
            }
        }
    }
}

// ---------------------------------------------------------------------------
// pv_f16: out[t,c] = sum_s P_un[s,t]*scale[s]*v[s,c] — pure f16 GEMM.
// scale[s] = f16(exp(m[s,jc0] - C_s)), jc0 = blockIdx.y (64-t tile aligns
// with one energy chunk). A-frag = P_un * scale via v_pk_mul_f16 (4 inst).
// 64t x 128c tile, 4 waves (2x2), acc[2][4], grid (NZ,16,4) = 1024 blocks.
// launch_bounds(256,5): LDS 28KB x5 = 140KB fits -> 5 blocks/CU TLP.
// ---------------------------------------------------------------------------
__global__ __launch_bounds__(256, 5) void pv_f16(
    const _Float16* __restrict__ Epk, const _Float16* __restrict__ Vpk,
    const _Float16* __restrict__ Xp, const float* __restrict__ G,
    const float* __restrict__ part, float* __restrict__ Out, int h0, int NC)
{
    __shared__ _Float16 lsP[2][2048];   // [s-chunk 0..3][t 0..63] pack8
    __shared__ _Float16 lsV[2][4096];   // [s-chunk 0..3][c 0..127] pack8
    __shared__ _Float16 lsS[1024];      // scale[s] for this (z, jc0)
    const int zl = blockIdx.x;
    const int b = zl & 1, hloc = zl >> 1;
    const int h = h0 + hloc;
    const _Float16* az = Epk + (size_t)zl * Ss * Ss;

    const int t = threadIdx.x;
    const int lane = t & 63, wave = t >> 6;
    const int quad = lane >> 4, l15 = lane & 15;
    const int tb = blockIdx.y * 64;     // t-block (A / M side)
    const int cb = blockIdx.z * 128;    // c-block (B / N side)
    const int tw = (wave >> 1) * 32, cw = (wave & 1) * 64;
    const int jc0 = blockIdx.y;         // energy 64-t-chunk of this tile

    // P staging: thread t -> s-chunk t>>6 (0..3), t-col t&63: 1 GLOAD/step
    const _Float16* pg = az + ((size_t)(t >> 6) * Ss + tb + (t & 63)) * 8;
    const _Float16* vg = Vpk + (((size_t)((b * Ss) >> 3) + (t >> 7)) * NC
                                + hloc * Dd + cb + (t & 127)) * 8;
    const size_t acs = (size_t)Ss * 8;
    const size_t vcs = (size_t)NC * 8;

    f32x4 acc[2][4] = {};
    GLOAD16(pg,           &lsP[0][t * 8]);
    GLOAD16(vg,           &lsV[0][t * 8]);
    GLOAD16(vg + 2 * vcs, &lsV[0][t * 8 + 2048]);
    // ---- merge partials -> C_s -> scale[s] = exp(m_jc0 - C_s) ----
    {
        const float* pz = part + (size_t)zl * 16 * 1024 * 2;
        for (int ss = t; ss < 1024; ss += 256) {
            const float* p = pz + (size_t)ss * 2;
            float m = -3.4e38f;
#pragma unroll
            for (int j = 0; j < 16; j++) m = fmaxf(m, p[(size_t)j * 2048]);
            float l = 0.0f;
#pragma unroll
            for (int j = 0; j < 16; j++)
                l += p[(size_t)j * 2048 + 1] * __expf(p[(size_t)j * 2048] - m);
            const float C = m + __logf(l);
            lsS[ss] = (_Float16)__expf(p[(size_t)jc0 * 2048] - C);
        }
    }
    __syncthreads();
    int cur = 0;
    for (int kb = 0; kb < Ss; kb += 32) {
        if (kb + 32 < Ss) {
            const int nb = cur ^ 1;
            GLOAD16(pg + ((size_t)(kb >> 3) + 4) * acs, &lsP[nb][t * 8]);
            GLOAD16(vg + ((size_t)(kb >> 3) + 4) * vcs, &lsV[nb][t * 8]);
            GLOAD16(vg + ((size_t)(kb >> 3) + 6) * vcs, &lsV[nb][t * 8 + 2048]);
        }
        const f16x8 sc8 = *(const f16x8*)&lsS[kb + quad * 8];
        f16x8 af[2], bf[4];
#pragma unroll
        for (int mi = 0; mi < 2; mi++) {
            const f16x8 pu = *(const f16x8*)&lsP[cur][quad * 512 + (tw + mi * 16 + l15) * 8];
            af[mi] = pu * sc8;          // v_pk_mul_f16 x4
        }
#pragma unroll
        for (int ni = 0; ni < 4; ni++)
            bf[ni] = *(const f16x8*)&lsV[cur][quad * 1024 + (cw + ni * 16 + l15) * 8];
#pragma unroll
        for (int mi = 0; mi < 2; mi++)
#pragma unroll
            for (int ni = 0; ni < 4; ni++)
                acc[mi][ni] = __builtin_amdgcn_mfma_f32_16x16x32_f16(af[mi], bf[ni], acc[mi][ni], 0, 0, 0);
        __syncthreads();
        cur ^= 1;
    }

    const float g = G[h];
    const float inv = 1.0f / (g + 1.0f);
#pragma unroll
    for (int mi = 0; mi < 2; mi++) {
        const int tr0 = tb + tw + mi * 16 + quad * 4;
#pragma unroll
        for (int r = 0; r < 4; r++) {
            const int tt = tr0 + r;
            const _Float16* xrow = Xp + (size_t)(b * Ss + tt) * Dd;
            float* orow = Out + ((size_t)((b * Hh + h) * Ss + tt)) * Dd;
#pragma unroll
            for (int ni = 0; ni < 4; ni++) {
                const int c = cb + cw + ni * 16 + l15;
                orow[c] = (g * acc[mi][ni][r] + (float)xrow[c]) * inv;
            }
        }
    }
}

// ---------------------------------------------------------------------------
// Workspace:
//   Wbuf  (HG==8 ? 4 : 1) slots of 512*NC f16 (slot 3 = Wp)
//   q, k  [2048][NC] f16 row-major
//   v     [2048][NC] f16 k-pack8 over rows
//   xp    [2048][512] f16
//   en    [NZ][1024][1024] f16 s-pack8 P_un  (xf/yf staging aliases its head)
//   part  [NZ][16][1024][2] f32
// HG=4 ~46 MiB (fits 62 MiB floor); HG=8 ~101 MiB (needs >=128 MiB)
// ---------------------------------------------------------------------------
extern "C" void kernel_launch(void* const* d_in, const int* in_sizes, int n_in,
                              void* d_out, int out_size, void* d_ws, size_t ws_size,
                              hipStream_t stream) {
    const float* x    = (const float*)d_in[0];
    const float* y    = (const float*)d_in[1];
    const float* Wq   = (const float*)d_in[2];
    const float* bq   = (const float*)d_in[3];
    const float* Wk   = (const float*)d_in[4];
    const float* bk   = (const float*)d_in[5];
    const float* Wv   = (const float*)d_in[6];
    const float* bv   = (const float*)d_in[7];
    const float* Wp   = (const float*)d_in[8];
    const float* gm   = (const float*)d_in[9];
    const int*   mask = (const int*)d_in[10];

    const int HG = (ws_size >= (size_t)134217728) ? 8 : 4;   // heads per group
    const int NC = HG * Dd;
    const int NZ = 2 * HG;                                    // z per group
    const size_t wslot = (size_t)512 * NC;                    // f16 per W slot

    char* ws = (char*)d_ws;
    size_t off = 0;
    _Float16* Wbuf = (_Float16*)(ws + off); off += (size_t)(HG == 8 ? 4 : 1) * wslot * 2;
    _Float16* qb   = (_Float16*)(ws + off); off += (size_t)Mm * NC * 2;
    _Float16* kb   = (_Float16*)(ws + off); off += (size_t)Mm * NC * 2;
    _Float16* vb   = (_Float16*)(ws + off); off += (size_t)Mm * NC * 2;
    _Float16* xp   = (_Float16*)(ws + off); off += (size_t)Mm * Dd * 2;
    _Float16* en   = (_Float16*)(ws + off); off += (size_t)NZ * Ss * Ss * 2;
    float*    part = (float*)(ws + off);    off += (size_t)NZ * 16 * 1024 * 2 * 4;
    _Float16* xf   = en;                      // staging inside en region
    _Float16* yf   = en + (size_t)Mm * 512;

    dim3 blk(256);
    const int NXY = Mm * 512;

    if (HG == 8) {
        stage_all<<<dim3(5248), blk, 0, stream>>>(x, y, Wq, Wk, Wv, Wp,
                                                  xf, yf, Wbuf, NC, wslot);
        proj_flat<<<dim3(1600), blk, 0, stream>>>(xf, yf, Wbuf, wslot,
                                                  bq, bk, bv, qb, kb, vb, xp);
        energy_f16<<<dim3(NZ, 8, 8), blk, 0, stream>>>(qb, kb, mask, en, part, NC);
        pv_f16<<<dim3(NZ, 16, 4), blk, 0, stream>>>(en, vb, xp, gm, part,
                                                    (float*)d_out, 0, NC);
    } else {
        // xp = x @ Wp (no bias)
        cvt_f16<<<dim3(NXY / 1024), blk, 0, stream>>>(x, xf, NXY);
        cvt_w_pk<<<dim3(2, 64), blk, 0, stream>>>(Wp, Dd, 0, Wbuf, Dd);
        proj_f16<<<dim3(4, 16), blk, 0, stream>>>(xf, Wbuf, nullptr, 0, xp, Dd, 0);

        for (int h0 = 0; h0 < Hh; h0 += HG) {
            // re-stage x/y (en region clobbered by previous group's energy)
            cvt_f16<<<dim3(NXY / 1024), blk, 0, stream>>>(x, xf, NXY);
            cvt_f16<<<dim3(NXY / 1024), blk, 0, stream>>>(y, yf, NXY);

            cvt_w_pk<<<dim3(NC / 256, 64), blk, 0, stream>>>(Wq, HD, h0 * Dd, Wbuf, NC);
            proj_f16<<<dim3(NC / 128, 16), blk, 0, stream>>>(xf, Wbuf, bq, h0 * Dd, qb, NC, 0);
            cvt_w_pk<<<dim3(NC / 256, 64), blk, 0, stream>>>(Wk, HD, h0 * Dd, Wbuf, NC);
            proj_f16<<<dim3(NC / 128, 16), blk, 0, stream>>>(yf, Wbuf, bk, h0 * Dd, kb, NC, 0);
            cvt_w_pk<<<dim3(NC / 256, 64), blk, 0, stream>>>(Wv, HD, h0 * Dd, Wbuf, NC);
            proj_f16<<<dim3(NC / 128, 16), blk, 0, stream>>>(yf, Wbuf, bv, h0 * Dd, vb, NC, 1);

            energy_f16<<<dim3(NZ, 8, 8), blk, 0, stream>>>(qb, kb, mask, en, part, NC);
            pv_f16<<<dim3(NZ, 16, 4), blk, 0, stream>>>(en, vb, xp, gm, part,
                                                        (float*)d_out, h0, NC);
        }
    }
}

// Round 13
// 205.070 us; speedup vs baseline: 1.1570x; 1.1570x over previous
//
#include <hip/hip_runtime.h>
#include <stdint.h>

// Problem constants (fp32 inputs/outputs)
#define Bb 2
#define Ss 1024
#define Dd 512
#define Hh 8
#define HD 4096   // Hh*Dd
#define Mm 2048   // Bb*Ss

typedef _Float16 f16x8 __attribute__((ext_vector_type(8)));
typedef _Float16 f16x4 __attribute__((ext_vector_type(4)));
typedef float    f32x4 __attribute__((ext_vector_type(4)));

#define LOG2E 1.44269504f

// async global->LDS, 16B per lane. dest must be linear: base + lane*16.
#define GLOAD16(g, l)                                                          \
    __builtin_amdgcn_global_load_lds(                                          \
        (const __attribute__((address_space(1))) void*)(g),                    \
        (__attribute__((address_space(3))) void*)(l), 16, 0, 0)

// ---------------------------------------------------------------------------
// cvt_f16: fp32 -> f16 elementwise. n multiple of 1024. (HG=4 fallback)
// ---------------------------------------------------------------------------
__global__ __launch_bounds__(256) void cvt_f16(
    const float* __restrict__ in, _Float16* __restrict__ out, int n)
{
    int i = (blockIdx.x * 256 + threadIdx.x) * 4;
    if (i < n) {
        float4 u = *(const float4*)(in + i);
        f16x4 o;
        o[0] = (_Float16)u.x; o[1] = (_Float16)u.y;
        o[2] = (_Float16)u.z; o[3] = (_Float16)u.w;
        *(f16x4*)(out + i) = o;
    }
}

// ---------------------------------------------------------------------------
// cvt_w_pk: W fp32 [512][ld], cols [col0, col0+NC) -> f16 k-pack8 (HG=4 path)
// ---------------------------------------------------------------------------
__global__ __launch_bounds__(256) void cvt_w_pk(
    const float* __restrict__ W, int ld, int col0,
    _Float16* __restrict__ out, int NC)
{
    const int n  = blockIdx.x * 256 + threadIdx.x;
    const int k0 = blockIdx.y * 8;
    f16x8 o;
#pragma unroll
    for (int j = 0; j < 8; j++)
        o[j] = (_Float16)W[(size_t)(k0 + j) * ld + col0 + n];
    *(f16x8*)(out + ((size_t)(k0 >> 3) * NC + n) * 8) = o;
}

// ---------------------------------------------------------------------------
// stage_all (HG=8): one flat grid doing ALL input staging.
//   jobs [0,1024)      : x fp32->f16   (1024 elems/block)
//   jobs [1024,2048)   : y fp32->f16
//   jobs [2048,5120)   : Wq/Wk/Wv -> k-pack8 (1024 blocks each, 16x64 decode)
//   jobs [5120,5248)   : Wp -> k-pack8       (128 blocks, 2x64 decode)
// ---------------------------------------------------------------------------
__global__ __launch_bounds__(256) void stage_all(
    const float* __restrict__ x, const float* __restrict__ y,
    const float* __restrict__ Wq, const float* __restrict__ Wk,
    const float* __restrict__ Wv, const float* __restrict__ Wp,
    _Float16* __restrict__ xf, _Float16* __restrict__ yf,
    _Float16* __restrict__ Wbuf, int NCq, size_t wslot)
{
    const int f = blockIdx.x;
    if (f < 2048) {
        const float* in = (f < 1024) ? x : y;
        _Float16* out   = (f < 1024) ? xf : yf;
        const int i = ((f & 1023) * 256 + threadIdx.x) * 4;
        float4 u = *(const float4*)(in + i);
        f16x4 o;
        o[0] = (_Float16)u.x; o[1] = (_Float16)u.y;
        o[2] = (_Float16)u.z; o[3] = (_Float16)u.w;
        *(f16x4*)(out + i) = o;
        return;
    }
    int l = f - 2048;
    const float* W; int ld, NCz, z, bx, by;
    if (l < 3072) {
        z = l >> 10; l &= 1023;
        W = (z == 0) ? Wq : (z == 1) ? Wk : Wv; ld = HD; NCz = NCq;
        bx = l & 15; by = l >> 4;
    } else {
        z = 3; l -= 3072;
        W = Wp; ld = Dd; NCz = Dd;
        bx = l & 1; by = l >> 1;
    }
    const int n  = bx * 256 + threadIdx.x;
    const int k0 = by * 8;
    f16x8 o;
#pragma unroll
    for (int j = 0; j < 8; j++)
        o[j] = (_Float16)W[(size_t)(k0 + j) * ld + n];
    *(f16x8*)(Wbuf + (size_t)z * wslot + ((size_t)(k0 >> 3) * NCz + n) * 8) = o;
}

// ---------------------------------------------------------------------------
// proj_body: C[2048, NC] = A[2048,512](f16 row-major) @ Wpk(k-pack8) + bias.
// 128x128 tile, 4 waves, 64x64/wave, 2-phase dbuf LDS via global_load_lds.
// packC=1 stores f16x4 (pack8 rows r=0..3 contiguous halves).
// ---------------------------------------------------------------------------
__device__ __forceinline__ void proj_body(
    const _Float16* __restrict__ A, const _Float16* __restrict__ Wpk,
    const float* __restrict__ bias, int bias0,
    _Float16* __restrict__ C, int NC, int packC, int bx, int by)
{
    __shared__ _Float16 lsA[2][4096];
    __shared__ _Float16 lsB[2][4096];
    const int t = threadIdx.x;
    const int lane = t & 63, wave = t >> 6;
    const int quad = lane >> 4, l15 = lane & 15;
    const int m0b = by * 128, n0b = bx * 128;
    const int aw = (wave >> 1) * 64, bw = (wave & 1) * 64;
    const int qx = (quad ^ ((l15 >> 2) & 3)) * 8;

    const _Float16* ag = A + (size_t)(m0b + (t >> 2)) * Dd
                           + ((t & 3) ^ ((t >> 4) & 3)) * 8;
    const _Float16* bg = Wpk + ((size_t)(t >> 7) * NC + n0b + (t & 127)) * 8;
    const size_t arj = (size_t)64 * Dd;
    const size_t bcs = (size_t)NC * 8;

    f32x4 acc[4][4] = {};
    GLOAD16(ag,           &lsA[0][t * 8]);
    GLOAD16(ag + arj,     &lsA[0][t * 8 + 2048]);
    GLOAD16(bg,           &lsB[0][t * 8]);
    GLOAD16(bg + 2 * bcs, &lsB[0][t * 8 + 2048]);
    __syncthreads();
    int cur = 0;
    for (int kb = 0; kb < Dd; kb += 32) {
        if (kb + 32 < Dd) {
            const int nb = cur ^ 1;
            GLOAD16(ag + kb + 32,       &lsA[nb][t * 8]);
            GLOAD16(ag + arj + kb + 32, &lsA[nb][t * 8 + 2048]);
            GLOAD16(bg + (size_t)((kb >> 3) + 4) * bcs, &lsB[nb][t * 8]);
            GLOAD16(bg + (size_t)((kb >> 3) + 6) * bcs, &lsB[nb][t * 8 + 2048]);
        }
        f16x8 af[4], bf[4];
#pragma unroll
        for (int mi = 0; mi < 4; mi++)
            af[mi] = *(const f16x8*)&lsA[cur][(aw + mi * 16 + l15) * 32 + qx];
#pragma unroll
        for (int ni = 0; ni < 4; ni++)
            bf[ni] = *(const f16x8*)&lsB[cur][quad * 1024 + (bw + ni * 16 + l15) * 8];
#pragma unroll
        for (int mi = 0; mi < 4; mi++)
#pragma unroll
            for (int ni = 0; ni < 4; ni++)
                acc[mi][ni] = __builtin_amdgcn_mfma_f32_16x16x32_f16(af[mi], bf[ni], acc[mi][ni], 0, 0, 0);
        __syncthreads();
        cur ^= 1;
    }

#pragma unroll
    for (int mi = 0; mi < 4; mi++) {
        const int row0 = m0b + aw + mi * 16 + quad * 4;
#pragma unroll
        for (int ni = 0; ni < 4; ni++) {
            const int col = n0b + bw + ni * 16 + l15;
            const float bv = bias ? bias[bias0 + col] : 0.0f;
            if (packC) {
                f16x4 o;
#pragma unroll
                for (int r = 0; r < 4; r++) o[r] = (_Float16)(acc[mi][ni][r] + bv);
                *(f16x4*)(C + ((size_t)(row0 >> 3) * NC + col) * 8 + (row0 & 7)) = o;
            } else {
#pragma unroll
                for (int r = 0; r < 4; r++)
                    C[(size_t)(row0 + r) * NC + col] = (_Float16)(acc[mi][ni][r] + bv);
            }
        }
    }
}

__global__ __launch_bounds__(256, 4) void proj_f16(
    const _Float16* __restrict__ A, const _Float16* __restrict__ Wpk,
    const float* __restrict__ bias, int bias0,
    _Float16* __restrict__ C, int NC, int packC)
{
    proj_body(A, Wpk, bias, bias0, C, NC, packC, blockIdx.x, blockIdx.y);
}

// fused q/k/v/xp projection (HG=8 only, NC=4096): FLAT 1600-block grid —
// jobs 0..1535 = q/k/v 128x128 tiles (512 each), 1536..1599 = xp tiles.
__global__ __launch_bounds__(256, 4) void proj_flat(
    const _Float16* __restrict__ xf, const _Float16* __restrict__ yf,
    const _Float16* __restrict__ Wpk, size_t wslot,
    const float* __restrict__ bq, const float* __restrict__ bk,
    const float* __restrict__ bv,
    _Float16* __restrict__ qb, _Float16* __restrict__ kb,
    _Float16* __restrict__ vb, _Float16* __restrict__ xp)
{
    const int f = blockIdx.x;
    int z, bx, by;
    if (f < 1536) { z = f >> 9; const int r = f & 511; bx = r & 31; by = r >> 5; }
    else         { z = 3;      const int r = f - 1536; bx = r & 3;  by = r >> 2; }
    const _Float16* A = (z == 0 || z == 3) ? xf : yf;
    const _Float16* W = Wpk + (size_t)z * wslot;
    const float* bias = (z == 0) ? bq : (z == 1) ? bk : (z == 2) ? bv : nullptr;
    _Float16* C = (z == 0) ? qb : (z == 1) ? kb : (z == 2) ? vb : xp;
    const int NCz = (z == 3) ? Dd : (Hh * Dd);
    proj_body(A, W, bias, 0, C, NCz, z == 2, bx, by);
}

// ---------------------------------------------------------------------------
// energy_f16: E[s,t] = sum_c q[s,c]*k[t,c]; masked t -> -30000.
// A = Q rows (M = s), B = K rows (N = t). STORES P_un = f16(exp(E - m))
// per (s, 64-t-chunk) in s-pack8 layout (reuses the exps already computed
// for the sum partials). Stats (m, l = sum exp) from f16-ROUNDED values.
// pv multiplies by scale[s] = exp(m_chunk - C_s) to recover P.
// Grid (NZ, 8, 8): z in blockIdx.x (XCD affinity).
// ---------------------------------------------------------------------------
__global__ __launch_bounds__(256, 4) void energy_f16(
    const _Float16* __restrict__ Q, const _Float16* __restrict__ Kb,
    const int* __restrict__ mask, _Float16* __restrict__ E,
    float* __restrict__ part, int NC)
{
    __shared__ _Float16 lsA[2][4096];
    __shared__ _Float16 lsB[2][4096];
    const int zl = blockIdx.x;
    const int b = zl & 1, hloc = zl >> 1;
    const _Float16* qz = Q + (size_t)b * Ss * NC + hloc * Dd;
    const _Float16* kz = Kb + (size_t)b * Ss * NC + hloc * Dd;
    _Float16* Ez = E + (size_t)zl * Ss * Ss;

    const int t = threadIdx.x;
    const int lane = t & 63, wave = t >> 6;
    const int quad = lane >> 4, l15 = lane & 15;
    const int sb = blockIdx.y * 128;    // s-block (A / M side, from Q)
    const int tb = blockIdx.z * 128;    // t-block (B / N side, from K)
    const int sw = (wave >> 1) * 64, tw = (wave & 1) * 64;
    const int qx = (quad ^ ((l15 >> 2) & 3)) * 8;

    const int sc = ((t & 3) ^ ((t >> 4) & 3)) * 8;   // pre-swizzled src chunk
    const _Float16* ag = qz + (size_t)(sb + (t >> 2)) * NC + sc;
    const _Float16* bg = kz + (size_t)(tb + (t >> 2)) * NC + sc;
    const size_t rj = (size_t)64 * NC;

    f32x4 acc[4][4] = {};
    GLOAD16(ag,      &lsA[0][t * 8]);
    GLOAD16(ag + rj, &lsA[0][t * 8 + 2048]);
    GLOAD16(bg,      &lsB[0][t * 8]);
    GLOAD16(bg + rj, &lsB[0][t * 8 + 2048]);
    __syncthreads();
    int cur = 0;
    for (int kb = 0; kb < Dd; kb += 32) {
        if (kb + 32 < Dd) {
            const int nb = cur ^ 1;
            GLOAD16(ag + kb + 32,      &lsA[nb][t * 8]);
            GLOAD16(ag + rj + kb + 32, &lsA[nb][t * 8 + 2048]);
            GLOAD16(bg + kb + 32,      &lsB[nb][t * 8]);
            GLOAD16(bg + rj + kb + 32, &lsB[nb][t * 8 + 2048]);
        }
        f16x8 af[4], bf[4];
#pragma unroll
        for (int mi = 0; mi < 4; mi++)
            af[mi] = *(const f16x8*)&lsA[cur][(sw + mi * 16 + l15) * 32 + qx];
#pragma unroll
        for (int ni = 0; ni < 4; ni++)
            bf[ni] = *(const f16x8*)&lsB[cur][(tw + ni * 16 + l15) * 32 + qx];
#pragma unroll
        for (int mi = 0; mi < 4; mi++)
#pragma unroll
            for (int ni = 0; ni < 4; ni++)
                acc[mi][ni] = __builtin_amdgcn_mfma_f32_16x16x32_f16(af[mi], bf[ni], acc[mi][ni], 0, 0, 0);
        __syncthreads();
        cur ^= 1;
    }

    // ---- mask (per column t) + round to f16 in place ----
#pragma unroll
    for (int ni = 0; ni < 4; ni++) {
        const int tcol = tb + tw + ni * 16 + l15;
        const int keep = mask[tcol];
#pragma unroll
        for (int mi = 0; mi < 4; mi++)
#pragma unroll
            for (int r = 0; r < 4; r++) {
                const float v = keep ? acc[mi][ni][r] : -30000.0f;
                acc[mi][ni][r] = (float)(_Float16)v;
            }
    }

    // ---- per-(s, 64-t-chunk): m, then store P_un = exp(E - m), then l ----
    const int jc = blockIdx.z * 2 + (wave & 1);          // t-chunk id 0..15
    float* ps = part + ((size_t)(zl * 16 + jc) * 1024) * 2;
#pragma unroll
    for (int mi = 0; mi < 4; mi++) {
        const int s0 = sb + sw + mi * 16 + quad * 4;
        _Float16* base = Ez + (size_t)(s0 >> 3) * (Ss * 8) + (s0 & 7);
        float m[4], l[4];
#pragma unroll
        for (int r = 0; r < 4; r++) {
            float mm = fmaxf(fmaxf(acc[mi][0][r], acc[mi][1][r]),
                             fmaxf(acc[mi][2][r], acc[mi][3][r]));
#pragma unroll
            for (int off = 1; off < 16; off <<= 1) mm = fmaxf(mm, __shfl_xor(mm, off));
            m[r] = mm;
            l[r] = 0.0f;
        }
#pragma unroll
        for (int ni = 0; ni < 4; ni++) {
            const int tcol = tb + tw + ni * 16 + l15;
            f16x4 o;
#pragma unroll
            for (int r = 0; r < 4; r++) {
                const float p = __expf(acc[mi][ni][r] - m[r]);
                l[r] += p;
                o[r] = (_Float16)p;
            }
            *(f16x4*)(base + (size_t)tcol * 8) = o;
        }
#pragma unroll
        for (int r = 0; r < 4; r++) {
            float ll = l[r];
#pragma unroll
            for (int off = 1; off < 16; off <<= 1) ll += __shfl_xor(ll, off);
            if (l15 == 0) {
                const int s = s0 + r;
                ps[s * 2]     = m[r];
                ps[s * 2 + 1] = ll;
            }
        }
    }
}

// ---------------------------------------------------------------------------
// pv_f16: out[t,c] = sum_s P_un[s,t]*scale[s]*v[s,c] — pure f16 GEMM.
// scale[s] = f16(exp(m[s,jc0] - C_s)), jc0 = blockIdx.y (64-t tile aligns
// with one energy chunk). A-frag = P_un * scale via v_pk_mul_f16 (4 inst).
// 64t x 128c tile, 4 waves (2x2), acc[2][4], grid (NZ,16,4) = 1024 blocks
// = full 4-blocks/CU residency.
// ---------------------------------------------------------------------------
__global__ __launch_bounds__(256, 4) void pv_f16(
    const _Float16* __restrict__ Epk, const _Float16* __restrict__ Vpk,
    const _Float16* __restrict__ Xp, const float* __restrict__ G,
    const float* __restrict__ part, float* __restrict__ Out, int h0, int NC)
{
    __shared__ _Float16 lsP[2][2048];   // [s-chunk 0..3][t 0..63] pack8
    __shared__ _Float16 lsV[2][4096];   // [s-chunk 0..3][c 0..127] pack8
    __shared__ _Float16 lsS[1024];      // scale[s] for this (z, jc0)
    const int zl = blockIdx.x;
    const int b = zl & 1, hloc = zl >> 1;
    const int h = h0 + hloc;
    const _Float16* az = Epk + (size_t)zl * Ss * Ss;

    const int t = threadIdx.x;
    const int lane = t & 63, wave = t >> 6;
    const int quad = lane >> 4, l15 = lane & 15;
    const int tb = blockIdx.y * 64;     // t-block (A / M side)
    const int cb = blockIdx.z * 128;    // c-block (B / N side)
    const int tw = (wave >> 1) * 32, cw = (wave & 1) * 64;
    const int jc0 = blockIdx.y;         // energy 64-t-chunk of this tile

    // P staging: thread t -> s-chunk t>>6 (0..3), t-col t&63: 1 GLOAD/step
    const _Float16* pg = az + ((size_t)(t >> 6) * Ss + tb + (t & 63)) * 8;
    const _Float16* vg = Vpk + (((size_t)((b * Ss) >> 3) + (t >> 7)) * NC
                                + hloc * Dd + cb + (t & 127)) * 8;
    const size_t acs = (size_t)Ss * 8;
    const size_t vcs = (size_t)NC * 8;

    f32x4 acc[2][4] = {};
    GLOAD16(pg,           &lsP[0][t * 8]);
    GLOAD16(vg,           &lsV[0][t * 8]);
    GLOAD16(vg + 2 * vcs, &lsV[0][t * 8 + 2048]);
    // ---- merge partials -> C_s -> scale[s] = exp(m_jc0 - C_s) ----
    {
        const float* pz = part + (size_t)zl * 16 * 1024 * 2;
        for (int ss = t; ss < 1024; ss += 256) {
            const float* p = pz + (size_t)ss * 2;
            float m = -3.4e38f;
#pragma unroll
            for (int j = 0; j < 16; j++) m = fmaxf(m, p[(size_t)j * 2048]);
            float l = 0.0f;
#pragma unroll
            for (int j = 0; j < 16; j++)
                l += p[(size_t)j * 2048 + 1] * __expf(p[(size_t)j * 2048] - m);
            const float C = m + __logf(l);
            lsS[ss] = (_Float16)__expf(p[(size_t)jc0 * 2048] - C);
        }
    }
    __syncthreads();
    int cur = 0;
    for (int kb = 0; kb < Ss; kb += 32) {
        if (kb + 32 < Ss) {
            const int nb = cur ^ 1;
            GLOAD16(pg + ((size_t)(kb >> 3) + 4) * acs, &lsP[nb][t * 8]);
            GLOAD16(vg + ((size_t)(kb >> 3) + 4) * vcs, &lsV[nb][t * 8]);
            GLOAD16(vg + ((size_t)(kb >> 3) + 6) * vcs, &lsV[nb][t * 8 + 2048]);
        }
        const f16x8 sc8 = *(const f16x8*)&lsS[kb + quad * 8];
        f16x8 af[2], bf[4];
#pragma unroll
        for (int mi = 0; mi < 2; mi++) {
            const f16x8 pu = *(const f16x8*)&lsP[cur][quad * 512 + (tw + mi * 16 + l15) * 8];
            af[mi] = pu * sc8;          // v_pk_mul_f16 x4
        }
#pragma unroll
        for (int ni = 0; ni < 4; ni++)
            bf[ni] = *(const f16x8*)&lsV[cur][quad * 1024 + (cw + ni * 16 + l15) * 8];
#pragma unroll
        for (int mi = 0; mi < 2; mi++)
#pragma unroll
            for (int ni = 0; ni < 4; ni++)
                acc[mi][ni] = __builtin_amdgcn_mfma_f32_16x16x32_f16(af[mi], bf[ni], acc[mi][ni], 0, 0, 0);
        __syncthreads();
        cur ^= 1;
    }

    const float g = G[h];
    const float inv = 1.0f / (g + 1.0f);
#pragma unroll
    for (int mi = 0; mi < 2; mi++) {
        const int tr0 = tb + tw + mi * 16 + quad * 4;
#pragma unroll
        for (int r = 0; r < 4; r++) {
            const int tt = tr0 + r;
            const _Float16* xrow = Xp + (size_t)(b * Ss + tt) * Dd;
            float* orow = Out + ((size_t)((b * Hh + h) * Ss + tt)) * Dd;
#pragma unroll
            for (int ni = 0; ni < 4; ni++) {
                const int c = cb + cw + ni * 16 + l15;
                orow[c] = (g * acc[mi][ni][r] + (float)xrow[c]) * inv;
            }
        }
    }
}

// ---------------------------------------------------------------------------
// Workspace:
//   Wbuf  (HG==8 ? 4 : 1) slots of 512*NC f16 (slot 3 = Wp)
//   q, k  [2048][NC] f16 row-major
//   v     [2048][NC] f16 k-pack8 over rows
//   xp    [2048][512] f16
//   en    [NZ][1024][1024] f16 s-pack8 P_un  (xf/yf staging aliases its head)
//   part  [NZ][16][1024][2] f32
// HG=4 ~46 MiB (fits 62 MiB floor); HG=8 ~101 MiB (needs >=128 MiB)
// ---------------------------------------------------------------------------
extern "C" void kernel_launch(void* const* d_in, const int* in_sizes, int n_in,
                              void* d_out, int out_size, void* d_ws, size_t ws_size,
                              hipStream_t stream) {
    const float* x    = (const float*)d_in[0];
    const float* y    = (const float*)d_in[1];
    const float* Wq   = (const float*)d_in[2];
    const float* bq   = (const float*)d_in[3];
    const float* Wk   = (const float*)d_in[4];
    const float* bk   = (const float*)d_in[5];
    const float* Wv   = (const float*)d_in[6];
    const float* bv   = (const float*)d_in[7];
    const float* Wp   = (const float*)d_in[8];
    const float* gm   = (const float*)d_in[9];
    const int*   mask = (const int*)d_in[10];

    const int HG = (ws_size >= (size_t)134217728) ? 8 : 4;   // heads per group
    const int NC = HG * Dd;
    const int NZ = 2 * HG;                                    // z per group
    const size_t wslot = (size_t)512 * NC;                    // f16 per W slot

    char* ws = (char*)d_ws;
    size_t off = 0;
    _Float16* Wbuf = (_Float16*)(ws + off); off += (size_t)(HG == 8 ? 4 : 1) * wslot * 2;
    _Float16* qb   = (_Float16*)(ws + off); off += (size_t)Mm * NC * 2;
    _Float16* kb   = (_Float16*)(ws + off); off += (size_t)Mm * NC * 2;
    _Float16* vb   = (_Float16*)(ws + off); off += (size_t)Mm * NC * 2;
    _Float16* xp   = (_Float16*)(ws + off); off += (size_t)Mm * Dd * 2;
    _Float16* en   = (_Float16*)(ws + off); off += (size_t)NZ * Ss * Ss * 2;
    float*    part = (float*)(ws + off);    off += (size_t)NZ * 16 * 1024 * 2 * 4;
    _Float16* xf   = en;                      // staging inside en region
    _Float16* yf   = en + (size_t)Mm * 512;

    dim3 blk(256);
    const int NXY = Mm * 512;

    if (HG == 8) {
        stage_all<<<dim3(5248), blk, 0, stream>>>(x, y, Wq, Wk, Wv, Wp,
                                                  xf, yf, Wbuf, NC, wslot);
        proj_flat<<<dim3(1600), blk, 0, stream>>>(xf, yf, Wbuf, wslot,
                                                  bq, bk, bv, qb, kb, vb, xp);
        energy_f16<<<dim3(NZ, 8, 8), blk, 0, stream>>>(qb, kb, mask, en, part, NC);
        pv_f16<<<dim3(NZ, 16, 4), blk, 0, stream>>>(en, vb, xp, gm, part,
                                                    (float*)d_out, 0, NC);
    } else {
        // xp = x @ Wp (no bias)
        cvt_f16<<<dim3(NXY / 1024), blk, 0, stream>>>(x, xf, NXY);
        cvt_w_pk<<<dim3(2, 64), blk, 0, stream>>>(Wp, Dd, 0, Wbuf, Dd);
        proj_f16<<<dim3(4, 16), blk, 0, stream>>>(xf, Wbuf, nullptr, 0, xp, Dd, 0);

        for (int h0 = 0; h0 < Hh; h0 += HG) {
            // re-stage x/y (en region clobbered by previous group's energy)
            cvt_f16<<<dim3(NXY / 1024), blk, 0, stream>>>(x, xf, NXY);
            cvt_f16<<<dim3(NXY / 1024), blk, 0, stream>>>(y, yf, NXY);

            cvt_w_pk<<<dim3(NC / 256, 64), blk, 0, stream>>>(Wq, HD, h0 * Dd, Wbuf, NC);
            proj_f16<<<dim3(NC / 128, 16), blk, 0, stream>>>(xf, Wbuf, bq, h0 * Dd, qb, NC, 0);
            cvt_w_pk<<<dim3(NC / 256, 64), blk, 0, stream>>>(Wk, HD, h0 * Dd, Wbuf, NC);
            proj_f16<<<dim3(NC / 128, 16), blk, 0, stream>>>(yf, Wbuf, bk, h0 * Dd, kb, NC, 0);
            cvt_w_pk<<<dim3(NC / 256, 64), blk, 0, stream>>>(Wv, HD, h0 * Dd, Wbuf, NC);
            proj_f16<<<dim3(NC / 128, 16), blk, 0, stream>>>(yf, Wbuf, bv, h0 * Dd, vb, NC, 1);

            energy_f16<<<dim3(NZ, 8, 8), blk, 0, stream>>>(qb, kb, mask, en, part, NC);
            pv_f16<<<dim3(NZ, 16, 4), blk, 0, stream>>>(en, vb, xp, gm, part,
                                                        (float*)d_out, h0, NC);
        }
    }
}